// Round 1
// 285.849 us; speedup vs baseline: 1.5108x; 1.5108x over previous
//
#include <hip/hip_runtime.h>
#include <math.h>

// Problem constants (fixed by the reference's setup_inputs)
constexpr int N_  = 2;
constexpr int E_  = 16;
constexpr int C_  = 32;
constexpr int V_  = 48 * 160 * 160;   // 1,228,800 voxels per batch
constexpr int V4_ = V_ / 4;           // 307,200 float4 groups per batch
constexpr int BLK = 256;

constexpr float DELTA_VAR  = 0.5f;
constexpr float DELTA_DIST = 2.0f;
constexpr float GAMMA      = 0.001f;

// 8-way split accumulators to kill same-line atomic serialization.
// ws layout (floats):
//   [0, 8192)     gsumT8 [k][n][e][c]   (k = blockIdx.x & 7)
//   [8192, 8704)  gcnt8  [k][n][c]
//   [8704, 8706)  gvar   [n]
constexpr int NCOPY   = 8;
constexpr int WS_SUMT = 0;
constexpr int WS_CNT  = WS_SUMT + NCOPY * N_ * E_ * C_;   // 8192
constexpr int WS_VAR  = WS_CNT  + NCOPY * N_ * C_;        // 8704
constexpr int WS_FLOATS = WS_VAR + N_;                    // 8706

using short8 = __attribute__((ext_vector_type(8))) short;
using f32x4  = __attribute__((ext_vector_type(4))) float;

__device__ __forceinline__ unsigned short f2bf(float f) {
    unsigned u = __float_as_uint(f);
    return (unsigned short)((u + 0x7FFFu + ((u >> 16) & 1u)) >> 16);
}
__device__ __forceinline__ unsigned packlab(int4 t) {
    return (unsigned)t.x | ((unsigned)t.y << 8) | ((unsigned)t.z << 16) | ((unsigned)t.w << 24);
}

// ---------------------------------------------------------------------------
// MFMA segmented sums + counts. Register prefetch, double-buffered LDS,
// ONE lgkm-only barrier per tile (prefetch + label loads stay in flight
// across it — no vmcnt drain). Epilogue: cross-wave LDS reduce, then one
// atomic per slot into 1-of-8 split copies.
// grid = (600, N), block = 256 (4 waves). Block owns 2048 voxels = 4 tiles.
// ---------------------------------------------------------------------------
constexpr int XPAD = 520;   // bf16 row stride for the 512-voxel tile
__global__ __launch_bounds__(BLK) void sums_mfma(
    const float4* __restrict__ x4, const int4* __restrict__ t4,
    float* __restrict__ ws)
{
    __shared__ unsigned short s_xb[2][E_ * XPAD];   // 33,280 B

    const int n     = blockIdx.y;
    const int gtile = blockIdx.x * 2048;
    const int tid   = threadIdx.x;
    const int lane  = tid & 63;
    const int wid   = tid >> 6;
    const int myc   = lane & 15;
    const int quad  = lane >> 4;

    const short one = 0x3F80;
    short8 A_ones = {one, one, one, one, one, one, one, one};

    f32x4 acc_lo = {0.f,0.f,0.f,0.f}, acc_hi = {0.f,0.f,0.f,0.f};
    f32x4 cnt_lo = {0.f,0.f,0.f,0.f}, cnt_hi = {0.f,0.f,0.f,0.f};

    // prologue: tile 0 loads
    float4 R[8];
    {
        const int tb4 = gtile >> 2;
        #pragma unroll
        for (int k = 0; k < 8; ++k) {
            const int i = k * BLK + tid, e = i >> 7, v4 = i & 127;
            R[k] = x4[((size_t)(n * E_ + e)) * V4_ + tb4 + v4];
        }
    }

    for (int t = 0; t < 4; ++t) {
        const int tbase4 = (gtile + t * 512) >> 2;
        unsigned short* buf = s_xb[t & 1];

        // convert + LDS stage (bf16; no global copy anymore)
        #pragma unroll
        for (int k = 0; k < 8; ++k) {
            const int i = k * BLK + tid, e = i >> 7, v4 = i & 127;
            uint2 p;
            p.x = (unsigned)f2bf(R[k].x) | ((unsigned)f2bf(R[k].y) << 16);
            p.y = (unsigned)f2bf(R[k].z) | ((unsigned)f2bf(R[k].w) << 16);
            *(uint2*)&buf[e * XPAD + v4 * 4] = p;
        }
        // prefetch next tile — stays in flight across the raw barrier
        if (t < 3) {
            const int nb4 = (gtile + (t + 1) * 512) >> 2;
            #pragma unroll
            for (int k = 0; k < 8; ++k) {
                const int i = k * BLK + tid, e = i >> 7, v4 = i & 127;
                R[k] = x4[((size_t)(n * E_ + e)) * V4_ + nb4 + v4];
            }
        }
        // labels for this tile's MFMA phase — issue BEFORE the barrier too
        const int wbase = wid * 128;
        int4 P[4], Q[4];
        #pragma unroll
        for (int s = 0; s < 4; ++s) {
            const int b4 = tbase4 + ((wbase + s * 32 + quad * 8) >> 2);
            P[s] = t4[(size_t)n * V4_ + b4];
            Q[s] = t4[(size_t)n * V4_ + b4 + 1];
        }

        // lgkm-only barrier: orders the ds_writes without draining vmcnt,
        // so the prefetch/label global loads remain outstanding.
        __builtin_amdgcn_sched_barrier(0);
        asm volatile("s_waitcnt lgkmcnt(0)");
        __builtin_amdgcn_s_barrier();
        __builtin_amdgcn_sched_barrier(0);

        // MFMA phase: 4 K-steps of 32 voxels over this wave's 128-voxel strip
        #pragma unroll
        for (int s = 0; s < 4; ++s) {
            const int lvb = wbase + s * 32;
            const short8 A = *(const short8*)&buf[myc * XPAD + lvb + quad * 8];
            const unsigned la = packlab(P[s]), lb2 = packlab(Q[s]);
            short8 Blo, Bhi;
            #pragma unroll
            for (int j = 0; j < 4; ++j) {
                const int c0 = (la  >> (8 * j)) & 255;
                const int c1 = (lb2 >> (8 * j)) & 255;
                Blo[j]     = (c0 == myc)      ? one : (short)0;
                Bhi[j]     = (c0 == myc + 16) ? one : (short)0;
                Blo[4 + j] = (c1 == myc)      ? one : (short)0;
                Bhi[4 + j] = (c1 == myc + 16) ? one : (short)0;
            }
            acc_lo = __builtin_amdgcn_mfma_f32_16x16x32_bf16(A, Blo, acc_lo, 0, 0, 0);
            acc_hi = __builtin_amdgcn_mfma_f32_16x16x32_bf16(A, Bhi, acc_hi, 0, 0, 0);
            cnt_lo = __builtin_amdgcn_mfma_f32_16x16x32_bf16(A_ones, Blo, cnt_lo, 0, 0, 0);
            cnt_hi = __builtin_amdgcn_mfma_f32_16x16x32_bf16(A_ones, Bhi, cnt_hi, 0, 0, 0);
        }
    }

    // ---- epilogue: cross-wave LDS reduce, then 512 (+32) atomics per BLOCK
    // (was 512 per WAVE) into one of 8 split copies (blockIdx.x & 7).
    // s_red uses only the first 8704 B of s_xb = buffer 0; the last tile's
    // MFMA reads were from buffer 1, and all waves passed barrier(t=3), so
    // all buffer-0 reads (tile 2) are long done.
    float* s_red = (float*)&s_xb[0][0];   // 2048 sums + 128 counts
    #pragma unroll
    for (int r = 0; r < 4; ++r) {
        s_red[wid * 512 + lane * 8 + r]     = acc_lo[r];
        s_red[wid * 512 + lane * 8 + 4 + r] = acc_hi[r];
    }
    if (quad == 0) {
        s_red[2048 + wid * 32 + myc]      = cnt_lo[0];
        s_red[2048 + wid * 32 + myc + 16] = cnt_hi[0];
    }
    __syncthreads();

    const int kc = blockIdx.x & (NCOPY - 1);
    float* gsumT = ws + WS_SUMT + kc * (N_ * E_ * C_);
    float* gcntk = ws + WS_CNT  + kc * (N_ * C_);
    #pragma unroll
    for (int u = 0; u < 2; ++u) {
        const int combo = tid * 2 + u;              // 0..511
        const int l = combo >> 3, k = combo & 7;
        const int e = (l >> 4) * 4 + (k & 3);
        const int c = (l & 15) + 16 * (k >> 2);
        const float v = s_red[combo] + s_red[512 + combo]
                      + s_red[1024 + combo] + s_red[1536 + combo];
        unsafeAtomicAdd(&gsumT[(n * E_ + e) * C_ + c], v);
    }
    if (tid < C_) {
        const float v = s_red[2048 + tid] + s_red[2048 + 32 + tid]
                      + s_red[2048 + 64 + tid] + s_red[2048 + 96 + tid];
        unsafeAtomicAdd(&gcntk[n * C_ + tid], v);
    }
}

// ---------------------------------------------------------------------------
// Variance: reads x directly in f32 (LLC-warm after sums; no bf16 copy).
// All 16 e-loads issued up front; mu built from the 8 split copies; block
// reduce -> ONE atomic per block.
// grid = (1200, N), block = 256.
// ---------------------------------------------------------------------------
constexpr int MUP = 20;
__global__ __launch_bounds__(BLK) void variance_f32(
    const float4* __restrict__ x4, const int4* __restrict__ t4,
    float* __restrict__ ws)
{
    __shared__ float s_mu[C_ * MUP];
    __shared__ float s_part[4];
    const float* gsumT = ws + WS_SUMT;
    const float* gcnt  = ws + WS_CNT;
    float*       gvar  = ws + WS_VAR;

    const int n = blockIdx.y, tid = threadIdx.x;
    const int v4g = blockIdx.x * BLK + tid;

    // issue the big loads first so they fly during the mu build
    const int4 t = t4[(size_t)n * V4_ + v4g];
    const float4* xrow = x4 + (size_t)n * E_ * V4_ + v4g;
    float4 xs[16];
    #pragma unroll
    for (int e = 0; e < 16; ++e) xs[e] = xrow[(size_t)e * V4_];

    for (int i = tid; i < C_ * E_; i += BLK) {
        const int c = i >> 4, e = i & 15;
        float s = 0.f, cc = 0.f;
        #pragma unroll
        for (int k = 0; k < NCOPY; ++k) {
            s  += gsumT[k * (N_ * E_ * C_) + (n * E_ + e) * C_ + c];
            cc += gcnt [k * (N_ * C_) + n * C_ + c];
        }
        s_mu[c * MUP + e] = s / cc;
        if (e == 0) s_mu[c * MUP + 16] = 1.0f / (cc * (float)C_);
    }
    __syncthreads();

    const int l0 = t.x, l1 = t.y, l2 = t.z, l3 = t.w;
    float4 m0[4], m1[4], m2[4], m3[4];
    #pragma unroll
    for (int u = 0; u < 4; ++u) {
        m0[u] = *(const float4*)&s_mu[l0 * MUP + 4 * u];
        m1[u] = *(const float4*)&s_mu[l1 * MUP + 4 * u];
        m2[u] = *(const float4*)&s_mu[l2 * MUP + 4 * u];
        m3[u] = *(const float4*)&s_mu[l3 * MUP + 4 * u];
    }
    const float w0 = s_mu[l0 * MUP + 16], w1 = s_mu[l1 * MUP + 16];
    const float w2 = s_mu[l2 * MUP + 16], w3 = s_mu[l3 * MUP + 16];

    float d0 = 0.f, d1 = 0.f, d2 = 0.f, d3 = 0.f;
    #pragma unroll
    for (int e = 0; e < 16; ++e) {
        const float mu0 = ((const float*)&m0[e >> 2])[e & 3];
        const float mu1 = ((const float*)&m1[e >> 2])[e & 3];
        const float mu2 = ((const float*)&m2[e >> 2])[e & 3];
        const float mu3 = ((const float*)&m3[e >> 2])[e & 3];
        d0 += (xs[e].x - mu0) * (xs[e].x - mu0);
        d1 += (xs[e].y - mu1) * (xs[e].y - mu1);
        d2 += (xs[e].z - mu2) * (xs[e].z - mu2);
        d3 += (xs[e].w - mu3) * (xs[e].w - mu3);
    }
    const float h0 = fmaxf(sqrtf(d0) - DELTA_VAR, 0.f);
    const float h1 = fmaxf(sqrtf(d1) - DELTA_VAR, 0.f);
    const float h2 = fmaxf(sqrtf(d2) - DELTA_VAR, 0.f);
    const float h3 = fmaxf(sqrtf(d3) - DELTA_VAR, 0.f);
    float v = h0 * h0 * w0 + h1 * h1 * w1 + h2 * h2 * w2 + h3 * h3 * w3;

    #pragma unroll
    for (int off = 32; off > 0; off >>= 1)
        v += __shfl_down(v, off, 64);
    if ((tid & 63) == 0) s_part[tid >> 6] = v;
    __syncthreads();
    if (tid == 0)
        unsafeAtomicAdd(&gvar[n], s_part[0] + s_part[1] + s_part[2] + s_part[3]);
}

// ---------------------------------------------------------------------------
// finalize: variance (precomputed) + pairwise repulsion + regularizer.
// Means rebuilt from the 8 split copies.
// ---------------------------------------------------------------------------
__global__ __launch_bounds__(BLK) void finalize(
    const float* __restrict__ ws, float* __restrict__ out)
{
    __shared__ float s_mean[C_ * 17];
    __shared__ float s_red;
    __shared__ float s_total;

    const float* gsumT = ws + WS_SUMT;
    const float* gcnt  = ws + WS_CNT;
    const float* gvar  = ws + WS_VAR;

    if (threadIdx.x == 0) s_total = 0.0f;

    for (int n = 0; n < N_; ++n) {
        __syncthreads();
        for (int i = threadIdx.x; i < C_ * E_; i += BLK) {
            const int c = i >> 4, e = i & 15;
            float s = 0.f, cc = 0.f;
            #pragma unroll
            for (int k = 0; k < NCOPY; ++k) {
                s  += gsumT[k * (N_ * E_ * C_) + (n * E_ + e) * C_ + c];
                cc += gcnt [k * (N_ * C_) + n * C_ + c];
            }
            s_mean[c * 17 + e] = s / cc;
        }
        if (threadIdx.x == 0) s_red = gvar[n];
        __syncthreads();

        float local = 0.0f;
        if (threadIdx.x < C_) {
            const int c = threadIdx.x;
            float d2 = 0.f;
            #pragma unroll
            for (int e = 0; e < E_; ++e) {
                const float m = s_mean[c * 17 + e];
                d2 += m * m;
            }
            const float nm = d2 > 0.f ? sqrtf(d2) : 0.f;
            local += GAMMA * nm / (float)C_;
        }
        for (int t = threadIdx.x; t < C_ * C_; t += BLK) {
            const int i = t >> 5, j = t & 31;
            if (i != j) {
                float d2 = 0.f;
                #pragma unroll
                for (int e = 0; e < E_; ++e) {
                    const float diff = s_mean[i * 17 + e] - s_mean[j * 17 + e];
                    d2 += diff * diff;
                }
                const float d = d2 > 0.f ? sqrtf(d2) : 0.f;
                const float h = fmaxf(2.0f * DELTA_DIST - d, 0.f);
                local += (h * h) / (float)(C_ * (C_ - 1));
            }
        }
        unsafeAtomicAdd(&s_red, local);
        __syncthreads();
        if (threadIdx.x == 0) s_total += s_red;
    }
    __syncthreads();
    if (threadIdx.x == 0) out[0] = s_total / (float)N_;
}

// ---------------------------------------------------------------------------
extern "C" void kernel_launch(void* const* d_in, const int* in_sizes, int n_in,
                              void* d_out, int out_size, void* d_ws, size_t ws_size,
                              hipStream_t stream) {
    const float4* x4 = (const float4*)d_in[0];
    const int4*   t4 = (const int4*)d_in[1];
    float* ws  = (float*)d_ws;
    float* out = (float*)d_out;

    hipMemsetAsync(d_ws, 0, WS_FLOATS * sizeof(float), stream);

    sums_mfma   <<<dim3(600, N_),        BLK, 0, stream>>>(x4, t4, ws);
    variance_f32<<<dim3(V4_ / BLK, N_),  BLK, 0, stream>>>(x4, t4, ws);
    finalize    <<<1, BLK, 0, stream>>>(ws, out);
}